// Round 6
// baseline (246.007 us; speedup 1.0000x reference)
//
#include <hip/hip_runtime.h>
#include <math.h>

#define B    128
#define CTRL 1024
#define NN   4096
#define MM   64
#define OD   70     // M + 6
#define NC   16     // n-chunks per batch
#define CHUNK 256   // NN / NC

// DPP-based 16-lane group sum (pure VALU, no LDS pipe).
#define DPP_ADD(v, ctrl)                                                        \
    do {                                                                        \
        int _t = __builtin_amdgcn_update_dpp(0, __float_as_int(v), (ctrl),      \
                                             0xF, 0xF, true);                   \
        (v) += __int_as_float(_t);                                              \
    } while (0)

__device__ inline float sum16(float v) {
    DPP_ADD(v, 0xB1);    // quad_perm xor1
    DPP_ADD(v, 0x4E);    // quad_perm xor2
    DPP_ADD(v, 0x141);   // row_half_mirror
    DPP_ADD(v, 0x140);   // row_mirror
    return v;
}

__device__ inline float dot4(float4 a, float4 b) {
    return a.x * b.x + a.y * b.y + a.z * b.z + a.w * b.w;
}

// ---------------- kernel 1: o = emb @ fc_w.T + fc_b ; zero accumulators -----
// grid(B), block 256 = 4 waves. Wave w computes j = w, w+4, ... (64-lane dots).
__global__ __launch_bounds__(256) void k_ctrl(const float* __restrict__ emb,
                                              const float* __restrict__ fc_w,
                                              const float* __restrict__ fc_b,
                                              float* __restrict__ o,
                                              float* __restrict__ zsum,
                                              float* __restrict__ psum,
                                              float* __restrict__ rnum) {
    int b = blockIdx.x;
    int t = threadIdx.x;
    int wv   = t >> 6;
    int lane = t & 63;

    if (t < MM) rnum[(size_t)b * MM + t] = 0.f;
    if (t == 254) zsum[b] = 0.f;
    if (t == 255) psum[b] = 0.f;

    const float4* e4 = (const float4*)(emb + (size_t)b * CTRL);
    float4 e0 = e4[lane * 4 + 0];
    float4 e1 = e4[lane * 4 + 1];
    float4 e2 = e4[lane * 4 + 2];
    float4 e3 = e4[lane * 4 + 3];

    for (int j = wv; j < OD; j += 4) {
        const float4* w4 = (const float4*)(fc_w + (size_t)j * CTRL);
        float s = dot4(e0, w4[lane * 4 + 0]) + dot4(e1, w4[lane * 4 + 1])
                + dot4(e2, w4[lane * 4 + 2]) + dot4(e3, w4[lane * 4 + 3]);
        for (int off = 32; off; off >>= 1) s += __shfl_xor(s, off);
        if (lane == 0) o[(size_t)b * OD + j] = s + fc_b[j];
    }
}

// ---------------- kernel 2: ev[b,n] = exp(beta*cos_sim) ; zsum[b] += ... ----
// grid (NC, B), block 256. 16 lanes per row; CHUNK rows per block.
__global__ __launch_bounds__(256) void k_sim(const float* __restrict__ mem,
                                             const float* __restrict__ o,
                                             float* __restrict__ ev_buf,
                                             float* __restrict__ zsum) {
    int b  = blockIdx.y;
    int n0 = blockIdx.x * CHUNK;
    int t  = threadIdx.x;

    __shared__ __align__(16) float k_sh[MM];
    __shared__ float kb[2];   // knorm, beta
    __shared__ float red[4];

    if (t < MM) k_sh[t] = o[(size_t)b * OD + t];
    __syncthreads();
    if (t == 0) {
        float ss = 0.f;
        for (int i = 0; i < MM; ++i) ss += k_sh[i] * k_sh[i];
        kb[0] = sqrtf(ss);
        float x = o[(size_t)b * OD + MM];
        kb[1] = fmaxf(x, 0.f) + log1pf(expf(-fabsf(x)));   // softplus -> beta
    }
    __syncthreads();
    float knorm = kb[0], beta = kb[1];

    int lane16 = t & 15;
    int rgrp   = t >> 4;
    float4 k4 = ((const float4*)k_sh)[lane16];

    float evsum = 0.f;
    #pragma unroll 8
    for (int i = 0; i < CHUNK / 16; ++i) {
        int n = n0 + rgrp + i * 16;
        const float4* m4 = (const float4*)(mem + ((size_t)b * NN + n) * MM);
        float4 v = m4[lane16];
        float dot = dot4(v, k4);
        float ssq = dot4(v, v);
        dot = sum16(dot);
        ssq = sum16(ssq);
        if (lane16 == 0) {
            // no max-shift: |beta*sim| <= ~5, exp fp32-safe; softmax shift-invariant
            float e = __expf(beta * dot / (knorm * sqrtf(ssq) + 1e-16f));
            ev_buf[(size_t)b * NN + n] = e;
            evsum += e;
        }
    }
    for (int off = 32; off; off >>= 1) evsum += __shfl_xor(evsum, off);
    if ((t & 63) == 0) red[t >> 6] = evsum;
    __syncthreads();
    if (t == 0) atomicAdd(&zsum[b], red[0] + red[1] + red[2] + red[3]);
}

// ---------------- kernel 3: wp = wt^gamma (LDS) ; psum += ; rnum += sweep ---
// grid (NC, B), block 256. powf overlaps the L3-served second memory sweep.
__global__ __launch_bounds__(256) void k_wr(const float* __restrict__ mem,
                                            const float* __restrict__ w_prev,
                                            const float* __restrict__ o,
                                            const float* __restrict__ ev_buf,
                                            const float* __restrict__ zsum,
                                            float* __restrict__ wp_buf,
                                            float* __restrict__ psum,
                                            float* __restrict__ rnum) {
    int c = blockIdx.x;
    int b = blockIdx.y;
    int t = threadIdx.x;
    int n0 = c * CHUNK;

    __shared__ float wg_sh[CHUNK + 2];
    __shared__ float wp_sh[CHUNK];
    __shared__ __align__(16) float4 acc_sh[256];
    __shared__ float red[4];

    // scalars (every thread, broadcast loads)
    const float* ob = o + (size_t)b * OD;
    float g  = 1.f / (1.f + __expf(-ob[MM + 1]));
    float a0 = ob[MM + 2], a1 = ob[MM + 3], a2 = ob[MM + 4];
    float mx = fmaxf(a0, fmaxf(a1, a2));
    float e0 = __expf(a0 - mx), e1 = __expf(a1 - mx), e2 = __expf(a2 - mx);
    float es = e0 + e1 + e2;
    float s0 = e0 / es, s1 = e1 / es, s2 = e2 / es;
    float xg = ob[MM + 5];
    float gamma = 1.f + fmaxf(xg, 0.f) + log1pf(__expf(-fabsf(xg)));
    float invsum = 1.f / zsum[b];

    size_t boff = (size_t)b * NN;
    for (int idx = t; idx < CHUNK + 2; idx += 256) {
        int n = (n0 - 1 + idx) & (NN - 1);
        wg_sh[idx] = g * ev_buf[boff + n] * invsum + (1.f - g) * w_prev[boff + n];
    }
    __syncthreads();

    float wt = s0 * wg_sh[t] + s1 * wg_sh[t + 1] + s2 * wg_sh[t + 2];
    float wp = __powf(wt, gamma);
    wp_sh[t] = wp;
    wp_buf[boff + n0 + t] = wp;

    float ps = wp;
    for (int off = 32; off; off >>= 1) ps += __shfl_xor(ps, off);
    if ((t & 63) == 0) red[t >> 6] = ps;
    __syncthreads();
    if (t == 0) atomicAdd(&psum[b], red[0] + red[1] + red[2] + red[3]);

    // ---- sweep 2: rnum[b,:] += sum_n wp[n] * mem[b,n,:] (L3-resident) ----
    int m4 = t & 15;
    int rg = t >> 4;
    float4 acc = {0.f, 0.f, 0.f, 0.f};
    const float4* base = (const float4*)(mem + (boff + n0) * MM);
    #pragma unroll 8
    for (int i = 0; i < CHUNK / 16; ++i) {
        int row = rg + i * 16;
        float4 v = base[(size_t)row * 16 + m4];
        float wv = wp_sh[row];
        acc.x += wv * v.x; acc.y += wv * v.y;
        acc.z += wv * v.z; acc.w += wv * v.w;
    }
    acc_sh[t] = acc;
    __syncthreads();
    if (t < 16) {
        float4 s = {0.f, 0.f, 0.f, 0.f};
        for (int j = 0; j < 16; ++j) {
            float4 v = acc_sh[t + j * 16];
            s.x += v.x; s.y += v.y; s.z += v.z; s.w += v.w;
        }
        float* rb = rnum + (size_t)b * MM + t * 4;
        atomicAdd(rb + 0, s.x);
        atomicAdd(rb + 1, s.y);
        atomicAdd(rb + 2, s.z);
        atomicAdd(rb + 3, s.w);
    }
}

// ---------------- kernel 4: normalize w and r by psum+eps -------------------
__global__ __launch_bounds__(256) void k_norm(const float* __restrict__ wp_buf,
                                              const float* __restrict__ psum,
                                              const float* __restrict__ rnum,
                                              float* __restrict__ r_out,
                                              float* __restrict__ w_out) {
    int c = blockIdx.x;
    int b = blockIdx.y;
    int t = threadIdx.x;
    float invz = 1.f / (psum[b] + 1e-16f);
    size_t boff = (size_t)b * NN + (size_t)c * CHUNK;
    w_out[boff + t] = wp_buf[boff + t] * invz;
    if (c == 0 && t < MM)
        r_out[(size_t)b * MM + t] = rnum[(size_t)b * MM + t] * invz;
}

// ---------------------------------------------------------------------------
extern "C" void kernel_launch(void* const* d_in, const int* in_sizes, int n_in,
                              void* d_out, int out_size, void* d_ws, size_t ws_size,
                              hipStream_t stream) {
    const float* emb    = (const float*)d_in[0];   // B x CTRL
    const float* w_prev = (const float*)d_in[1];   // B x N
    const float* mem    = (const float*)d_in[2];   // B x N x M
    const float* fc_w   = (const float*)d_in[3];   // OD x CTRL
    const float* fc_b   = (const float*)d_in[4];   // OD

    float* r_out = (float*)d_out;                  // B x M
    float* w_out = r_out + (size_t)B * MM;         // B x N

    // workspace layout (fp32)
    float* ev   = (float*)d_ws;                    // B x N
    float* wp   = ev + (size_t)B * NN;             // B x N
    float* o    = wp + (size_t)B * NN;             // B x OD
    float* zsum = o + (size_t)B * OD;              // B
    float* psum = zsum + B;                        // B
    float* rnum = psum + B;                        // B x M

    k_ctrl<<<dim3(B), 256, 0, stream>>>(emb, fc_w, fc_b, o, zsum, psum, rnum);
    k_sim <<<dim3(NC, B), 256, 0, stream>>>(mem, o, ev, zsum);
    k_wr  <<<dim3(NC, B), 256, 0, stream>>>(mem, w_prev, o, ev, zsum, wp, psum, rnum);
    k_norm<<<dim3(NC, B), 256, 0, stream>>>(wp, psum, rnum, r_out, w_out);
}

// Round 7
// 242.938 us; speedup vs baseline: 1.0126x; 1.0126x over previous
//
#include <hip/hip_runtime.h>
#include <math.h>

#define B    128
#define CTRL 1024
#define NN   4096
#define MM   64
#define OD   70     // M + 6
#define NC   8      // n-chunks per batch
#define CHUNK 512   // NN / NC

// DPP-based 16-lane group sum (pure VALU, no LDS pipe).
#define DPP_ADD(v, ctrl)                                                        \
    do {                                                                        \
        int _t = __builtin_amdgcn_update_dpp(0, __float_as_int(v), (ctrl),      \
                                             0xF, 0xF, true);                   \
        (v) += __int_as_float(_t);                                              \
    } while (0)

__device__ inline float sum16(float v) {
    DPP_ADD(v, 0xB1);    // quad_perm xor1
    DPP_ADD(v, 0x4E);    // quad_perm xor2
    DPP_ADD(v, 0x141);   // row_half_mirror
    DPP_ADD(v, 0x140);   // row_mirror
    return v;
}

__device__ inline float dot4(float4 a, float4 b) {
    return a.x * b.x + a.y * b.y + a.z * b.z + a.w * b.w;
}

// 64-lane dot of emb-row (preloaded regs) with fc_w row j, plus bias.
// Lane-major indexing: element q*64+lane (1 KB contiguous per instr).
__device__ inline float ctrl_dot(const float4 e[4], const float* fc_w,
                                 const float* fc_b, int j, int lane) {
    const float4* w4 = (const float4*)(fc_w + (size_t)j * CTRL);
    float s = dot4(e[0], w4[lane])       + dot4(e[1], w4[64 + lane])
            + dot4(e[2], w4[128 + lane]) + dot4(e[3], w4[192 + lane]);
    for (int off = 32; off; off >>= 1) s += __shfl_xor(s, off);
    return s + fc_b[j];   // valid in lane 0 (all lanes have sum anyway)
}

// ---------------- kernel 1: redundant ctrl (k,beta) + sweep 1 ---------------
// grid (NC, B), block 256. ev[b,n] = exp(beta*cos_sim(k, mem[b,n,:]));
// zpart[b*NC+c] = block partial of sum(ev). No atomics, no init needed.
__global__ __launch_bounds__(256) void k_sim(const float* __restrict__ mem,
                                             const float* __restrict__ emb,
                                             const float* __restrict__ fc_w,
                                             const float* __restrict__ fc_b,
                                             float* __restrict__ ev_buf,
                                             float* __restrict__ zpart) {
    int c  = blockIdx.x;
    int b  = blockIdx.y;
    int n0 = c * CHUNK;
    int t  = threadIdx.x;
    int wv   = t >> 6;
    int lane = t & 63;

    __shared__ __align__(16) float k_sh[MM];
    __shared__ float kb[2];   // knorm, beta
    __shared__ float red[4];

    // --- prologue: o[0..64] = emb[b] @ fc_w[0..64].T + fc_b (4 waves) ---
    {
        const float4* e4 = (const float4*)(emb + (size_t)b * CTRL);
        float4 e[4] = { e4[lane], e4[64 + lane], e4[128 + lane], e4[192 + lane] };
        for (int j = wv; j <= MM; j += 4) {
            float s = ctrl_dot(e, fc_w, fc_b, j, lane);
            if (lane == 0) {
                if (j < MM) k_sh[j] = s;
                else        kb[1] = fmaxf(s, 0.f) + log1pf(expf(-fabsf(s))); // beta
            }
        }
    }
    __syncthreads();
    if (t == 0) {
        float ss = 0.f;
        for (int i = 0; i < MM; ++i) ss += k_sh[i] * k_sh[i];
        kb[0] = sqrtf(ss);
    }
    __syncthreads();
    float knorm = kb[0], beta = kb[1];

    int lane16 = t & 15;
    int rgrp   = t >> 4;
    float4 k4 = ((const float4*)k_sh)[lane16];

    float evsum = 0.f;
    #pragma unroll 8
    for (int i = 0; i < CHUNK / 16; ++i) {
        int n = n0 + rgrp + i * 16;
        const float4* m4 = (const float4*)(mem + ((size_t)b * NN + n) * MM);
        float4 v = m4[lane16];
        float dot = dot4(v, k4);
        float ssq = dot4(v, v);
        dot = sum16(dot);
        ssq = sum16(ssq);
        if (lane16 == 0) {
            // no max-shift: |beta*sim| <= ~5, exp fp32-safe; softmax shift-invariant
            float e = __expf(beta * dot / (knorm * sqrtf(ssq) + 1e-16f));
            ev_buf[(size_t)b * NN + n] = e;
            evsum += e;
        }
    }
    for (int off = 32; off; off >>= 1) evsum += __shfl_xor(evsum, off);
    if ((t & 63) == 0) red[t >> 6] = evsum;
    __syncthreads();
    if (t == 0) zpart[b * NC + c] = red[0] + red[1] + red[2] + red[3];
}

// ---------------- kernel 2: wp = wt^gamma ; parts ; sweep 2 -----------------
// grid (NC, B), block 256. Writes wp_buf, ppart, rpart (no atomics).
__global__ __launch_bounds__(256) void k_wr(const float* __restrict__ mem,
                                            const float* __restrict__ w_prev,
                                            const float* __restrict__ emb,
                                            const float* __restrict__ fc_w,
                                            const float* __restrict__ fc_b,
                                            const float* __restrict__ ev_buf,
                                            const float* __restrict__ zpart,
                                            float* __restrict__ wp_buf,
                                            float* __restrict__ ppart,
                                            float* __restrict__ rpart) {
    int c  = blockIdx.x;
    int b  = blockIdx.y;
    int t  = threadIdx.x;
    int n0 = c * CHUNK;
    size_t boff = (size_t)b * NN;

    __shared__ float wg_sh[CHUNK + 2];
    __shared__ float wp_sh[CHUNK];
    __shared__ __align__(16) float4 acc_sh[256];
    __shared__ float red[4];
    __shared__ float scal[6];   // g, s0, s1, s2, gamma, invsum

    // issue wg input loads early (independent of prologue)
    float ev_r[3], pw_r[3];
    int   nidx[3];
    int nld = 0;
    for (int idx = t; idx < CHUNK + 2; idx += 256) {
        int n = (n0 - 1 + idx) & (NN - 1);
        ev_r[nld] = ev_buf[boff + n];
        pw_r[nld] = w_prev[boff + n];
        nidx[nld] = idx;
        ++nld;
    }

    // --- prologue: o[65..69] -> g, s0..s2, gamma ; zsum -> invsum (wave 0) ---
    if (t < 64) {
        const float4* e4 = (const float4*)(emb + (size_t)b * CTRL);
        float4 e[4] = { e4[t], e4[64 + t], e4[128 + t], e4[192 + t] };
        float o65 = ctrl_dot(e, fc_w, fc_b, MM + 1, t);
        float o66 = ctrl_dot(e, fc_w, fc_b, MM + 2, t);
        float o67 = ctrl_dot(e, fc_w, fc_b, MM + 3, t);
        float o68 = ctrl_dot(e, fc_w, fc_b, MM + 4, t);
        float o69 = ctrl_dot(e, fc_w, fc_b, MM + 5, t);
        if (t == 0) {
            float g  = 1.f / (1.f + __expf(-o65));
            float mx = fmaxf(o66, fmaxf(o67, o68));
            float e0 = __expf(o66 - mx), e1 = __expf(o67 - mx), e2 = __expf(o68 - mx);
            float es = e0 + e1 + e2;
            float gamma = 1.f + fmaxf(o69, 0.f) + log1pf(__expf(-fabsf(o69)));
            float zs = 0.f;
            for (int j = 0; j < NC; ++j) zs += zpart[b * NC + j];
            scal[0] = g; scal[1] = e0 / es; scal[2] = e1 / es; scal[3] = e2 / es;
            scal[4] = gamma; scal[5] = 1.f / zs;
        }
    }
    __syncthreads();
    float g = scal[0], s0 = scal[1], s1 = scal[2], s2 = scal[3];
    float gamma = scal[4], invsum = scal[5];

    for (int i = 0; i < nld; ++i)
        wg_sh[nidx[i]] = g * ev_r[i] * invsum + (1.f - g) * pw_r[i];
    __syncthreads();

    float wt0 = s0 * wg_sh[t]       + s1 * wg_sh[t + 1]   + s2 * wg_sh[t + 2];
    float wt1 = s0 * wg_sh[t + 256] + s1 * wg_sh[t + 257] + s2 * wg_sh[t + 258];
    float wp0 = __powf(wt0, gamma);
    float wp1 = __powf(wt1, gamma);
    wp_sh[t]       = wp0;
    wp_sh[t + 256] = wp1;
    wp_buf[boff + n0 + t]       = wp0;
    wp_buf[boff + n0 + t + 256] = wp1;

    float ps = wp0 + wp1;
    for (int off = 32; off; off >>= 1) ps += __shfl_xor(ps, off);
    if ((t & 63) == 0) red[t >> 6] = ps;
    __syncthreads();
    if (t == 0) ppart[b * NC + c] = red[0] + red[1] + red[2] + red[3];

    // ---- sweep 2: rpart[b,c,:] = sum_n wp[n] * mem[b,n,:] (L3-resident) ----
    int m4 = t & 15;
    int rg = t >> 4;
    float4 acc = {0.f, 0.f, 0.f, 0.f};
    const float4* base = (const float4*)(mem + (boff + n0) * MM);
    #pragma unroll 8
    for (int i = 0; i < CHUNK / 16; ++i) {
        int row = rg + i * 16;
        float4 v = base[(size_t)row * 16 + m4];
        float wv = wp_sh[row];
        acc.x += wv * v.x; acc.y += wv * v.y;
        acc.z += wv * v.z; acc.w += wv * v.w;
    }
    acc_sh[t] = acc;
    __syncthreads();
    if (t < 16) {
        float4 s = {0.f, 0.f, 0.f, 0.f};
        for (int j = 0; j < 16; ++j) {
            float4 v = acc_sh[t + j * 16];
            s.x += v.x; s.y += v.y; s.z += v.z; s.w += v.w;
        }
        ((float4*)(rpart + ((size_t)b * NC + c) * MM))[t] = s;
    }
}

// ---------------- kernel 3: psum ; normalize w and r ------------------------
// grid (B), block 256.
__global__ __launch_bounds__(256) void k_fin(const float* __restrict__ wp_buf,
                                             const float* __restrict__ ppart,
                                             const float* __restrict__ rpart,
                                             float* __restrict__ r_out,
                                             float* __restrict__ w_out) {
    int b = blockIdx.x;
    int t = threadIdx.x;

    __shared__ float sc[1];
    if (t == 0) {
        float psum = 0.f;
        for (int j = 0; j < NC; ++j) psum += ppart[b * NC + j];
        sc[0] = 1.f / (psum + 1e-16f);
    }
    __syncthreads();
    float invz = sc[0];

    if (t < MM) {
        float s = 0.f;
        for (int j = 0; j < NC; ++j) s += rpart[((size_t)b * NC + j) * MM + t];
        r_out[(size_t)b * MM + t] = s * invz;
    }

    const float4* wp4 = (const float4*)(wp_buf + (size_t)b * NN);
    float4*       wo4 = (float4*)(w_out + (size_t)b * NN);
    #pragma unroll
    for (int i = 0; i < NN / 4 / 256; ++i) {
        float4 v = wp4[t + i * 256];
        v.x *= invz; v.y *= invz; v.z *= invz; v.w *= invz;
        wo4[t + i * 256] = v;
    }
}

// ---------------------------------------------------------------------------
extern "C" void kernel_launch(void* const* d_in, const int* in_sizes, int n_in,
                              void* d_out, int out_size, void* d_ws, size_t ws_size,
                              hipStream_t stream) {
    const float* emb    = (const float*)d_in[0];   // B x CTRL
    const float* w_prev = (const float*)d_in[1];   // B x N
    const float* mem    = (const float*)d_in[2];   // B x N x M
    const float* fc_w   = (const float*)d_in[3];   // OD x CTRL
    const float* fc_b   = (const float*)d_in[4];   // OD

    float* r_out = (float*)d_out;                  // B x M
    float* w_out = r_out + (size_t)B * MM;         // B x N

    // workspace layout (fp32) — no zero-init required anywhere
    float* ev    = (float*)d_ws;                   // B x N
    float* wp    = ev + (size_t)B * NN;            // B x N
    float* zpart = wp + (size_t)B * NN;            // B x NC
    float* ppart = zpart + (size_t)B * NC;         // B x NC
    float* rpart = ppart + (size_t)B * NC;         // B x NC x M

    k_sim<<<dim3(NC, B), 256, 0, stream>>>(mem, emb, fc_w, fc_b, ev, zpart);
    k_wr <<<dim3(NC, B), 256, 0, stream>>>(mem, w_prev, emb, fc_w, fc_b,
                                           ev, zpart, wp, ppart, rpart);
    k_fin<<<dim3(B), 256, 0, stream>>>(wp, ppart, rpart, r_out, w_out);
}